// Round 9
// baseline (2401.784 us; speedup 1.0000x reference)
//
#include <hip/hip_runtime.h>
#include <stdint.h>

#define NSAMP 16
#define BATCH 128
#define SEQLEN 32
#define SDIM 8
#define ODIM 4
#define HID 800
#define MROWS (NSAMP * BATCH) /* 2048 */
#define KEEPP 0.8f

typedef __attribute__((ext_vector_type(8))) short short8v;
typedef __attribute__((ext_vector_type(4))) float float4v;

// ---------------- threefry2x32 (JAX partitionable mode, verified R1) ----------------
__host__ __device__ __forceinline__ void tf2x32(uint32_t k0, uint32_t k1,
                                                uint32_t x0, uint32_t x1,
                                                uint32_t& o0, uint32_t& o1) {
  uint32_t ks2 = k0 ^ k1 ^ 0x1BD11BDAu;
  x0 += k0; x1 += k1;
#define TFR(r) { x0 += x1; x1 = (x1 << (r)) | (x1 >> (32 - (r))); x1 ^= x0; }
  TFR(13) TFR(15) TFR(26) TFR(6)
  x0 += k1; x1 += ks2 + 1u;
  TFR(17) TFR(29) TFR(16) TFR(24)
  x0 += ks2; x1 += k0 + 2u;
  TFR(13) TFR(15) TFR(26) TFR(6)
  x0 += k0; x1 += k1 + 3u;
  TFR(17) TFR(29) TFR(16) TFR(24)
  x0 += k1; x1 += ks2 + 4u;
  TFR(13) TFR(15) TFR(26) TFR(6)
  x0 += ks2; x1 += k0 + 5u;
#undef TFR
  o0 = x0; o1 = x1;
}

__device__ __forceinline__ float bits_to_unit(uint32_t bits) {
  return __uint_as_float((bits >> 9) | 0x3F800000u) - 1.0f;
}

__device__ __forceinline__ float tf_uniform_part(uint32_t k0, uint32_t k1, uint32_t idx) {
  uint32_t b1, b2;
  tf2x32(k0, k1, 0u, idx, b1, b2);
  return bits_to_unit(b1 ^ b2);
}

__device__ __forceinline__ ushort f2bf(float f) {
  uint32_t u = __float_as_uint(f);
  uint32_t r = (u + 0x7FFFu + ((u >> 16) & 1u)) >> 16;
  return (ushort)r;
}

__device__ __forceinline__ void bar_sync() {
  __builtin_amdgcn_sched_barrier(0);
  __builtin_amdgcn_s_barrier();
  __builtin_amdgcn_sched_barrier(0);
}

// ---------------- weight conversion fp32 -> bf16 (once) ----------------
__global__ void convert_w_kernel(const float* __restrict__ W_ih, const float* __restrict__ W_hh,
                                 ushort* __restrict__ Wib, ushort* __restrict__ Whb) {
  int i = (blockIdx.x * 256 + threadIdx.x) * 4;
  if (i >= 2400 * HID) return;
  float4 v1 = *reinterpret_cast<const float4*>(W_ih + i);
  float4 v2 = *reinterpret_cast<const float4*>(W_hh + i);
  ushort4 o1, o2;
  o1.x = f2bf(v1.x); o1.y = f2bf(v1.y); o1.z = f2bf(v1.z); o1.w = f2bf(v1.w);
  o2.x = f2bf(v2.x); o2.y = f2bf(v2.y); o2.z = f2bf(v2.z); o2.w = f2bf(v2.w);
  *reinterpret_cast<ushort4*>(Wib + i) = o1;
  *reinterpret_cast<ushort4*>(Whb + i) = o2;
}

__global__ void transpose_wout_kernel(const float* __restrict__ W_out, float* __restrict__ WoutT) {
  int i = blockIdx.x * 256 + threadIdx.x;
  if (i < 32 * HID) {
    int o = i / HID, k = i - o * HID;
    WoutT[k * 32 + o] = W_out[i];
  }
}

// ---------------- a_ens = bf16( a * m1 / keep ) ----------------
__global__ void a_ens_kernel(const float* __restrict__ a, ushort* __restrict__ aeb,
                             uint32_t k0, uint32_t k1) {
  int base = (blockIdx.x * blockDim.x + threadIdx.x) * 4;
  if (base >= MROWS * HID) return;
  int row = base / HID;
  int b = row % BATCH;
  int col = base - row * HID;
  float4 av = *reinterpret_cast<const float4*>(a + b * HID + col);
  ushort4 ov;
#pragma unroll
  for (int q = 0; q < 4; ++q) {
    float u = tf_uniform_part(k0, k1, (uint32_t)(base + q));
    float f = (&av.x)[q] * ((u < KEEPP) ? 1.25f : 0.0f);
    (&ov.x)[q] = f2bf(f);
  }
  *reinterpret_cast<ushort4*>(aeb + base) = ov;
}

// ---------------- MFMA GRU: R4 structure retiled TM=128/TN=16 for 3 blocks/CU ---------
// Grid 800 (8 XCD x (2m x 50n)); LDS/buffer 22528B (A 2x8KB + B 6x1KB), x2 dbuf = 44KB
// -> 3 blocks/CU (135KB), 12 waves/CU. 24 staging segs/step (22 + 2 benign dups),
// 6 global_load_lds per wave -> uniform counted vmcnt(6). Same swizzle as R4 (0-conflict).
#define LDSBUF 22528

__global__ __launch_bounds__(256, 3) void gru_mfma_kernel(
    const ushort* __restrict__ aeb, const ushort* __restrict__ hb,
    const ushort* __restrict__ Wib, const ushort* __restrict__ Whb,
    const float* __restrict__ h_old,
    const float* __restrict__ b_ih, const float* __restrict__ b_hh,
    float* __restrict__ h_new, ushort* __restrict__ h_new_b) {
  __shared__ __align__(1024) char lds[2 * LDSBUF];

  const int tid = threadIdx.x;
  const int wid = tid >> 6;
  const int lane = tid & 63;

  const int bid = blockIdx.x;          // 0..799
  const int xcd = bid & 7;
  const int q = bid >> 3;              // 0..99
  const int mloc = q / 50;             // 0..1
  const int nblk = q - mloc * 50;      // 0..49
  const int m0 = (xcd * 2 + mloc) * 128;
  const int n0 = nblk * 16;

  float4v acc[6][2];
#pragma unroll
  for (int g = 0; g < 6; ++g)
#pragma unroll
    for (int mf = 0; mf < 2; ++mf)
      acc[g][mf] = (float4v)(0.0f);

  const int rlo = lane >> 2;                        // row/col within 16-row seg
  const int sslot = (lane & 3) ^ ((lane >> 3) & 3); // pre-swizzled source 16B slot
  const int kg = lane >> 4;                         // mfma k-group
  const int l15 = lane & 15;

  // ---- stage descriptors: wave wid handles i = s*4+wid, s=0..5 (24 segs, 22 unique)
  const ushort* gp[6];
  int ldso[6];
#pragma unroll
  for (int s = 0; s < 6; ++s) {
    int i = s * 4 + wid;               // 0..23
    if (i >= 22) i -= 22;              // segs 22,23 duplicate A segs 0,1 (same data)
    if (i < 16) {
      int src = i >> 3, i8 = i & 7;
      ldso[s] = src * 8192 + i8 * 1024;
      const ushort* base = src ? hb : aeb;
      gp[s] = base + (size_t)(m0 + i8 * 16 + rlo) * HID + sslot * 8;
    } else {
      int g = i - 16;                  // 0..5
      ldso[s] = 16384 + g * 1024;
      const ushort* base = (g < 3) ? Wib : Whb;
      int wrow = n0 + (g % 3) * HID + rlo;
      gp[s] = base + (size_t)wrow * HID + sslot * 8;
    }
  }

#define STAGE(BUF) do {                                                          \
    _Pragma("unroll")                                                            \
    for (int s = 0; s < 6; ++s) {                                                \
      __builtin_amdgcn_global_load_lds(                                          \
          (const __attribute__((address_space(1))) void*)gp[s],                  \
          (__attribute__((address_space(3))) void*)(lds + (BUF)*LDSBUF + ldso[s]),\
          16, 0, 0);                                                             \
      gp[s] += 32;                                                               \
    }                                                                            \
  } while (0)

#define COMPUTE(BUF) do {                                                        \
    const char* lb = lds + (BUF)*LDSBUF;                                         \
    short8v bfr[6];                                                              \
    _Pragma("unroll")                                                            \
    for (int g = 0; g < 6; ++g) {                                                \
      int off = 16384 + g * 1024 + l15 * 64 + ((kg ^ ((l15 >> 1) & 3)) << 4);    \
      bfr[g] = *reinterpret_cast<const short8v*>(lb + off);                      \
    }                                                                            \
    short8v afr[2][2];                                                           \
    _Pragma("unroll")                                                            \
    for (int src = 0; src < 2; ++src)                                            \
      _Pragma("unroll")                                                          \
      for (int mf = 0; mf < 2; ++mf) {                                           \
        int row = wid * 32 + mf * 16 + l15;                                      \
        int off = src * 8192 + row * 64 + ((kg ^ ((row >> 1) & 3)) << 4);        \
        afr[src][mf] = *reinterpret_cast<const short8v*>(lb + off);              \
      }                                                                          \
    __builtin_amdgcn_s_setprio(1);                                               \
    _Pragma("unroll")                                                            \
    for (int g = 0; g < 6; ++g) {                                                \
      const int src = (g < 3) ? 0 : 1;                                           \
      _Pragma("unroll")                                                          \
      for (int mf = 0; mf < 2; ++mf)                                             \
        acc[g][mf] = __builtin_amdgcn_mfma_f32_16x16x32_bf16(                    \
            afr[src][mf], bfr[g], acc[g][mf], 0, 0, 0);                          \
    }                                                                            \
    __builtin_amdgcn_s_setprio(0);                                               \
  } while (0)

  STAGE(0);
#pragma unroll 1
  for (int k = 0; k < 24; k += 2) {
    STAGE(1);
    asm volatile("s_waitcnt vmcnt(6)" ::: "memory");
    bar_sync();
    COMPUTE(0);
    bar_sync();
    STAGE(0);
    asm volatile("s_waitcnt vmcnt(6)" ::: "memory");
    bar_sync();
    COMPUTE(1);
    bar_sync();
  }
  asm volatile("s_waitcnt vmcnt(0)" ::: "memory");
  bar_sync();
  COMPUTE(0);

  // ---- epilogue: gates + state; C/D: col=lane&15, row=(lane>>4)*4+reg
  const int rowq = (lane >> 4) * 4;
  const int col = n0 + l15;
  const float bir = b_ih[col], biz = b_ih[col + HID], bin = b_ih[col + 2 * HID];
  const float bhr = b_hh[col], bhz = b_hh[col + HID], bhn = b_hh[col + 2 * HID];
#pragma unroll
  for (int mf = 0; mf < 2; ++mf) {
#pragma unroll
    for (int reg = 0; reg < 4; ++reg) {
      const int m = m0 + wid * 32 + mf * 16 + rowq + reg;
      float gir = acc[0][mf][reg] + bir;
      float giz = acc[1][mf][reg] + biz;
      float gin = acc[2][mf][reg] + bin;
      float ghr = acc[3][mf][reg] + bhr;
      float ghz = acc[4][mf][reg] + bhz;
      float ghn = acc[5][mf][reg] + bhn;
      float r = 1.0f / (1.0f + expf(-(gir + ghr)));
      float z = 1.0f / (1.0f + expf(-(giz + ghz)));
      float nval = tanhf(gin + r * ghn);
      float hv = h_old[(size_t)m * HID + col];
      float res = (1.0f - z) * nval + z * hv;
      h_new[(size_t)m * HID + col] = res;
      h_new_b[(size_t)m * HID + col] = f2bf(res);
    }
  }
#undef STAGE
#undef COMPUTE
}

// ---------------- K_vec = h_new @ W_out^T + b_out, dropout m2, ens (2048 blocks) -------
__global__ void kvec_ens_kernel(const float* __restrict__ h_new,
                                const float* __restrict__ WoutT,  // [HID][32]
                                const float* __restrict__ b_out,
                                const float* __restrict__ x_pred, // [B][8]
                                const float* __restrict__ innov,  // [B][4]
                                float* __restrict__ ens,          // [NS][B][8]
                                uint32_t k0, uint32_t k1) {
  const int jb = blockIdx.x;
  const int b = jb & (BATCH - 1);
  const int tid = threadIdx.x;
  const int o = tid & 31;
  const int kk = tid >> 5;

  const float* hrow = h_new + (size_t)jb * HID;
  float partial = 0.0f;
  for (int k = kk * 100; k < kk * 100 + 100; ++k)
    partial = fmaf(hrow[k], WoutT[k * 32 + o], partial);

  __shared__ float red[8][32];
  __shared__ float Kv[32];
  red[kk][o] = partial;
  __syncthreads();
  if (tid < 32) {
    float s = 0.0f;
#pragma unroll
    for (int q = 0; q < 8; ++q) s += red[q][tid];
    s += b_out[tid];
    float u = tf_uniform_part(k0, k1, (uint32_t)(jb * 32 + tid));
    Kv[tid] = (u < KEEPP) ? s * 1.25f : 0.0f;
  }
  __syncthreads();
  if (tid < SDIM) {
    float s = x_pred[b * SDIM + tid];
#pragma unroll
    for (int oo = 0; oo < ODIM; ++oo)
      s = fmaf(Kv[tid * ODIM + oo], innov[b * ODIM + oo], s);
    ens[jb * SDIM + tid] = s;
  }
}

// ---------------- ensemble stats + outputs + prep of next step (128 blocks) ------------
__global__ void reduce_prep_kernel(const float* __restrict__ ens,
                                   float* __restrict__ x_pred,
                                   float* __restrict__ innov,
                                   const float* __restrict__ y_seq,
                                   const float* __restrict__ W1,
                                   const float* __restrict__ b1,
                                   float* __restrict__ a,
                                   float* __restrict__ out_xs, float* __restrict__ out_Ps,
                                   int t) {
  const int b = blockIdx.x;
  const int tid = threadIdx.x;
  __shared__ float e[NSAMP][SDIM];
  __shared__ float xf[SDIM];
  __shared__ float dxs[SDIM];
  __shared__ float xpn[SDIM];
  __shared__ float inv[ODIM];
  __shared__ float nin[SDIM + ODIM];

  if (t >= 0) {
    if (tid < NSAMP * SDIM) {
      int j = tid >> 3, s = tid & 7;
      e[j][s] = ens[(j * BATCH + b) * SDIM + s];
    }
    __syncthreads();
    if (tid < SDIM) {
      float s = 0.0f;
#pragma unroll
      for (int j = 0; j < NSAMP; ++j) s += e[j][tid];
      s *= (1.0f / NSAMP);
      xf[tid] = s;
      out_xs[(b * SEQLEN + t) * SDIM + tid] = s;
      dxs[tid] = s - x_pred[b * SDIM + tid];
    }
    __syncthreads();
    if (tid < SDIM * SDIM) {
      int s = tid >> 3, u = tid & 7;
      float accv = 0.0f;
#pragma unroll
      for (int j = 0; j < NSAMP; ++j)
        accv += (e[j][s] - xf[s]) * (e[j][u] - xf[u]);
      out_Ps[((b * SEQLEN + t) * SDIM + s) * SDIM + u] = accv * (1.0f / NSAMP);
    }
  } else {
    if (tid < SDIM) { xf[tid] = 0.0f; dxs[tid] = 0.0f; }
  }
  if (t == SEQLEN - 1) return;
  __syncthreads();
  if (tid < SDIM) {
    float x = xf[tid];
    float xp = 0.9f * x + 0.1f * sinf(x);
    xpn[tid] = xp;
    x_pred[b * SDIM + tid] = xp;
  }
  __syncthreads();
  if (tid < ODIM) {
    float yh = tanhf(xpn[tid]);
    float iv = y_seq[(b * SEQLEN + (t + 1)) * ODIM + tid] - yh;
    inv[tid] = iv;
    innov[b * ODIM + tid] = iv;
  }
  __syncthreads();
  if (tid == 0) {
    float nd = 0.0f;
    for (int s = 0; s < SDIM; ++s) nd += dxs[s] * dxs[s];
    nd = fmaxf(sqrtf(nd), 1e-12f);
    for (int s = 0; s < SDIM; ++s) nin[s] = dxs[s] / nd;
    float ni = 0.0f;
    for (int o2 = 0; o2 < ODIM; ++o2) ni += inv[o2] * inv[o2];
    ni = fmaxf(sqrtf(ni), 1e-12f);
    for (int o2 = 0; o2 < ODIM; ++o2) nin[SDIM + o2] = inv[o2] / ni;
  }
  __syncthreads();
  for (int i = tid; i < HID; i += blockDim.x) {
    float s = b1[i];
#pragma unroll
    for (int c = 0; c < 12; ++c) s = fmaf(nin[c], W1[i * 12 + c], s);
    a[b * HID + i] = fmaxf(s, 0.0f);
  }
}

extern "C" void kernel_launch(void* const* d_in, const int* in_sizes, int n_in,
                              void* d_out, int out_size, void* d_ws, size_t ws_size,
                              hipStream_t stream) {
  (void)in_sizes; (void)n_in; (void)out_size; (void)ws_size;
  const float* y_seq = (const float*)d_in[0];
  const float* W1 = (const float*)d_in[1];
  const float* b1 = (const float*)d_in[2];
  const float* W_ih = (const float*)d_in[3];
  const float* W_hh = (const float*)d_in[4];
  const float* b_ih = (const float*)d_in[5];
  const float* b_hh = (const float*)d_in[6];
  const float* W_out = (const float*)d_in[7];
  const float* b_out = (const float*)d_in[8];

  char* ws = (char*)d_ws;
  size_t off = 0;
  float* h_a = (float*)(ws + off);    off += (size_t)MROWS * HID * 4;
  float* h_b = (float*)(ws + off);    off += (size_t)MROWS * HID * 4;
  ushort* hb_a = (ushort*)(ws + off); off += (size_t)MROWS * HID * 2;
  ushort* hb_b = (ushort*)(ws + off); off += (size_t)MROWS * HID * 2;
  ushort* aeb = (ushort*)(ws + off);  off += (size_t)MROWS * HID * 2;
  ushort* Wib = (ushort*)(ws + off);  off += (size_t)2400 * HID * 2;
  ushort* Whb = (ushort*)(ws + off);  off += (size_t)2400 * HID * 2;
  float* a_buf = (float*)(ws + off);  off += (size_t)BATCH * HID * 4;
  float* WoutT = (float*)(ws + off);  off += (size_t)HID * 32 * 4;
  float* x_pred = (float*)(ws + off); off += (size_t)BATCH * SDIM * 4;
  float* innov = (float*)(ws + off);  off += (size_t)BATCH * ODIM * 4;
  float* ens = (float*)(ws + off);    off += (size_t)NSAMP * BATCH * SDIM * 4;

  float* out_xs = (float*)d_out;
  float* out_Ps = out_xs + (size_t)BATCH * SEQLEN * SDIM;

  hipMemsetAsync(h_a, 0, (size_t)MROWS * HID * 4, stream);
  hipMemsetAsync(hb_a, 0, (size_t)MROWS * HID * 2, stream);
  convert_w_kernel<<<1875, 256, 0, stream>>>(W_ih, W_hh, Wib, Whb);
  transpose_wout_kernel<<<100, 256, 0, stream>>>(W_out, WoutT);
  reduce_prep_kernel<<<BATCH, 256, 0, stream>>>(ens, x_pred, innov, y_seq, W1, b1,
                                                a_buf, out_xs, out_Ps, -1);

  float* hc = h_a;  float* hn = h_b;
  ushort* hcb = hb_a; ushort* hnb = hb_b;
  for (int t = 0; t < SEQLEN; ++t) {
    uint32_t kt0, kt1, k1a, k1b, k2a, k2b;
    tf2x32(0u, 42u, 0u, (uint32_t)t, kt0, kt1);   // fold_in(key(42), t)
    tf2x32(kt0, kt1, 0u, 0u, k1a, k1b);           // dropout1 key
    tf2x32(kt0, kt1, 0u, 1u, k2a, k2b);           // dropout2 key

    a_ens_kernel<<<1600, 256, 0, stream>>>(a_buf, aeb, k1a, k1b);
    gru_mfma_kernel<<<800, 256, 0, stream>>>(aeb, hcb, Wib, Whb, hc, b_ih, b_hh, hn, hnb);
    kvec_ens_kernel<<<MROWS, 256, 0, stream>>>(hn, WoutT, b_out, x_pred, innov, ens, k2a, k2b);
    reduce_prep_kernel<<<BATCH, 256, 0, stream>>>(ens, x_pred, innov, y_seq, W1, b1,
                                                  a_buf, out_xs, out_Ps, t);
    float* tmp = hc; hc = hn; hn = tmp;
    ushort* tmpb = hcb; hcb = hnb; hnb = tmpb;
  }
}

// Round 10
// 2225.896 us; speedup vs baseline: 1.0790x; 1.0790x over previous
//
#include <hip/hip_runtime.h>
#include <stdint.h>

#define NSAMP 16
#define BATCH 128
#define SEQLEN 32
#define SDIM 8
#define ODIM 4
#define HID 800
#define MROWS (NSAMP * BATCH) /* 2048 */
#define KEEPP 0.8f

typedef __attribute__((ext_vector_type(8))) short short8v;
typedef __attribute__((ext_vector_type(4))) float float4v;

// ---------------- threefry2x32 (JAX partitionable mode, verified R1) ----------------
__host__ __device__ __forceinline__ void tf2x32(uint32_t k0, uint32_t k1,
                                                uint32_t x0, uint32_t x1,
                                                uint32_t& o0, uint32_t& o1) {
  uint32_t ks2 = k0 ^ k1 ^ 0x1BD11BDAu;
  x0 += k0; x1 += k1;
#define TFR(r) { x0 += x1; x1 = (x1 << (r)) | (x1 >> (32 - (r))); x1 ^= x0; }
  TFR(13) TFR(15) TFR(26) TFR(6)
  x0 += k1; x1 += ks2 + 1u;
  TFR(17) TFR(29) TFR(16) TFR(24)
  x0 += ks2; x1 += k0 + 2u;
  TFR(13) TFR(15) TFR(26) TFR(6)
  x0 += k0; x1 += k1 + 3u;
  TFR(17) TFR(29) TFR(16) TFR(24)
  x0 += k1; x1 += ks2 + 4u;
  TFR(13) TFR(15) TFR(26) TFR(6)
  x0 += ks2; x1 += k0 + 5u;
#undef TFR
  o0 = x0; o1 = x1;
}

__device__ __forceinline__ float bits_to_unit(uint32_t bits) {
  return __uint_as_float((bits >> 9) | 0x3F800000u) - 1.0f;
}

__device__ __forceinline__ float tf_uniform_part(uint32_t k0, uint32_t k1, uint32_t idx) {
  uint32_t b1, b2;
  tf2x32(k0, k1, 0u, idx, b1, b2);
  return bits_to_unit(b1 ^ b2);
}

__device__ __forceinline__ ushort f2bf(float f) {
  uint32_t u = __float_as_uint(f);
  uint32_t r = (u + 0x7FFFu + ((u >> 16) & 1u)) >> 16;
  return (ushort)r;
}

__device__ __forceinline__ void bar_sync() {
  __builtin_amdgcn_sched_barrier(0);
  __builtin_amdgcn_s_barrier();
  __builtin_amdgcn_sched_barrier(0);
}

// ---------------- weight conversion fp32 -> bf16 (once) ----------------
__global__ void convert_w_kernel(const float* __restrict__ W_ih, const float* __restrict__ W_hh,
                                 ushort* __restrict__ Wib, ushort* __restrict__ Whb) {
  int i = (blockIdx.x * 256 + threadIdx.x) * 4;
  if (i >= 2400 * HID) return;
  float4 v1 = *reinterpret_cast<const float4*>(W_ih + i);
  float4 v2 = *reinterpret_cast<const float4*>(W_hh + i);
  ushort4 o1, o2;
  o1.x = f2bf(v1.x); o1.y = f2bf(v1.y); o1.z = f2bf(v1.z); o1.w = f2bf(v1.w);
  o2.x = f2bf(v2.x); o2.y = f2bf(v2.y); o2.z = f2bf(v2.z); o2.w = f2bf(v2.w);
  *reinterpret_cast<ushort4*>(Wib + i) = o1;
  *reinterpret_cast<ushort4*>(Whb + i) = o2;
}

__global__ void transpose_wout_kernel(const float* __restrict__ W_out, float* __restrict__ WoutT) {
  int i = blockIdx.x * 256 + threadIdx.x;
  if (i < 32 * HID) {
    int o = i / HID, k = i - o * HID;
    WoutT[k * 32 + o] = W_out[i];
  }
}

// ---------------- a_ens = bf16( a * m1 / keep ) ----------------
__global__ void a_ens_kernel(const float* __restrict__ a, ushort* __restrict__ aeb,
                             uint32_t k0, uint32_t k1) {
  int base = (blockIdx.x * blockDim.x + threadIdx.x) * 4;
  if (base >= MROWS * HID) return;
  int row = base / HID;
  int b = row % BATCH;
  int col = base - row * HID;
  float4 av = *reinterpret_cast<const float4*>(a + b * HID + col);
  ushort4 ov;
#pragma unroll
  for (int q = 0; q < 4; ++q) {
    float u = tf_uniform_part(k0, k1, (uint32_t)(base + q));
    float f = (&av.x)[q] * ((u < KEEPP) ? 1.25f : 0.0f);
    (&ov.x)[q] = f2bf(f);
  }
  *reinterpret_cast<ushort4*>(aeb + base) = ov;
}

// ====================== R4 kernel (verified 45.6us) — shared macros ======================
#define LDSBUF 28672

#define GRU_DESCRIPTORS                                                          \
  const int rlo = lane >> 2;                                                     \
  const int sslot = (lane & 3) ^ ((lane >> 3) & 3);                              \
  const int kg = lane >> 4;                                                      \
  const int l15 = lane & 15;                                                     \
  const ushort* gp[7];                                                           \
  const ushort* gp0[7];                                                          \
  int ldso[7];                                                                   \
  _Pragma("unroll")                                                              \
  for (int s = 0; s < 7; ++s) {                                                  \
    int i = s * 4 + wid;                                                         \
    if (i < 16) {                                                                \
      int src = i >> 3, i8 = i & 7;                                              \
      ldso[s] = src * 8192 + i8 * 1024;                                          \
      const ushort* base = src ? hb : aeb;                                       \
      gp[s] = base + (size_t)(m0 + i8 * 16 + rlo) * HID + sslot * 8;             \
    } else {                                                                     \
      int j = i - 16, g = j >> 1, half = j & 1;                                  \
      ldso[s] = 16384 + g * 2048 + half * 1024;                                  \
      const ushort* base = (g < 3) ? Wib : Whb;                                  \
      int wrow = n0 + (g % 3) * HID + half * 16 + rlo;                           \
      gp[s] = base + (size_t)wrow * HID + sslot * 8;                             \
    }                                                                            \
    gp0[s] = gp[s];                                                              \
  }

#define STAGE(BUF) do {                                                          \
    _Pragma("unroll")                                                            \
    for (int s = 0; s < 7; ++s) {                                                \
      __builtin_amdgcn_global_load_lds(                                          \
          (const __attribute__((address_space(1))) void*)gp[s],                  \
          (__attribute__((address_space(3))) void*)(lds + (BUF)*LDSBUF + ldso[s]),\
          16, 0, 0);                                                             \
      gp[s] += 32;                                                               \
    }                                                                            \
  } while (0)

#define COMPUTE(BUF) do {                                                        \
    const char* lb = lds + (BUF)*LDSBUF;                                         \
    short8v bfr[6][2];                                                           \
    _Pragma("unroll")                                                            \
    for (int g = 0; g < 6; ++g)                                                  \
      _Pragma("unroll")                                                          \
      for (int nf = 0; nf < 2; ++nf) {                                           \
        int row = nf * 16 + l15;                                                 \
        int off = 16384 + g * 2048 + row * 64 + ((kg ^ ((row >> 1) & 3)) << 4);  \
        bfr[g][nf] = *reinterpret_cast<const short8v*>(lb + off);                \
      }                                                                          \
    short8v afr[2][2];                                                           \
    _Pragma("unroll")                                                            \
    for (int src = 0; src < 2; ++src)                                            \
      _Pragma("unroll")                                                          \
      for (int mf = 0; mf < 2; ++mf) {                                           \
        int row = wid * 32 + mf * 16 + l15;                                      \
        int off = src * 8192 + row * 64 + ((kg ^ ((row >> 1) & 3)) << 4);        \
        afr[src][mf] = *reinterpret_cast<const short8v*>(lb + off);              \
      }                                                                          \
    _Pragma("unroll")                                                            \
    for (int g = 0; g < 6; ++g) {                                                \
      const int src = (g < 3) ? 0 : 1;                                           \
      _Pragma("unroll")                                                          \
      for (int mf = 0; mf < 2; ++mf)                                             \
        _Pragma("unroll")                                                        \
        for (int nf = 0; nf < 2; ++nf)                                           \
          acc[g][mf][nf] = __builtin_amdgcn_mfma_f32_16x16x32_bf16(              \
              afr[src][mf], bfr[g][nf], acc[g][mf][nf], 0, 0, 0);                \
    }                                                                            \
  } while (0)

__global__ __launch_bounds__(256, 2) void gru_mfma_kernel(
    const ushort* __restrict__ aeb, const ushort* __restrict__ hb,
    const ushort* __restrict__ Wib, const ushort* __restrict__ Whb,
    const float* __restrict__ h_old,
    const float* __restrict__ b_ih, const float* __restrict__ b_hh,
    float* __restrict__ h_new, ushort* __restrict__ h_new_b) {
  __shared__ __align__(1024) char lds[2 * LDSBUF];
  const int tid = threadIdx.x;
  const int wid = tid >> 6;
  const int lane = tid & 63;
  const int m0 = blockIdx.x * 128;
  const int n0 = blockIdx.y * 32;

  float4v acc[6][2][2];
#pragma unroll
  for (int g = 0; g < 6; ++g)
#pragma unroll
    for (int mf = 0; mf < 2; ++mf)
#pragma unroll
      for (int nf = 0; nf < 2; ++nf)
        acc[g][mf][nf] = (float4v)(0.0f);

  GRU_DESCRIPTORS

  STAGE(0);
#pragma unroll 1
  for (int k = 0; k < 24; k += 2) {
    STAGE(1);
    asm volatile("s_waitcnt vmcnt(7)" ::: "memory");
    bar_sync();
    COMPUTE(0);
    bar_sync();
    STAGE(0);
    asm volatile("s_waitcnt vmcnt(7)" ::: "memory");
    bar_sync();
    COMPUTE(1);
    bar_sync();
  }
  asm volatile("s_waitcnt vmcnt(0)" ::: "memory");
  bar_sync();
  COMPUTE(0);

  const int rowq = (lane >> 4) * 4;
#pragma unroll
  for (int nf = 0; nf < 2; ++nf) {
    const int col = n0 + nf * 16 + l15;
    const float bir = b_ih[col], biz = b_ih[col + HID], bin = b_ih[col + 2 * HID];
    const float bhr = b_hh[col], bhz = b_hh[col + HID], bhn = b_hh[col + 2 * HID];
#pragma unroll
    for (int mf = 0; mf < 2; ++mf) {
#pragma unroll
      for (int reg = 0; reg < 4; ++reg) {
        const int m = m0 + wid * 32 + mf * 16 + rowq + reg;
        float gir = acc[0][mf][nf][reg] + bir;
        float giz = acc[1][mf][nf][reg] + biz;
        float gin = acc[2][mf][nf][reg] + bin;
        float ghr = acc[3][mf][nf][reg] + bhr;
        float ghz = acc[4][mf][nf][reg] + bhz;
        float ghn = acc[5][mf][nf][reg] + bhn;
        float r = 1.0f / (1.0f + expf(-(gir + ghr)));
        float z = 1.0f / (1.0f + expf(-(giz + ghz)));
        float nval = tanhf(gin + r * ghn);
        float hv = h_old[(size_t)m * HID + col];
        float res = (1.0f - z) * nval + z * hv;
        h_new[(size_t)m * HID + col] = res;
        h_new_b[(size_t)m * HID + col] = f2bf(res);
      }
    }
  }
}

// ====================== Ablation probes: 4 reps of the R4 K-loop =========================
// MODE 0 = full pipeline; 1 = no staging (compute+barriers only);
// MODE 2 = staging+barriers only (no ds_read/MFMA); 3 = full minus barriers.
// Writes checksum to scratch only; outputs unaffected. Rep-amplified so each probe's
// per-dispatch duration is readable from the rocprof table (top-5).
template <int MODE>
__global__ __launch_bounds__(256, 2) void gru_probe_kernel(
    const ushort* __restrict__ aeb, const ushort* __restrict__ hb,
    const ushort* __restrict__ Wib, const ushort* __restrict__ Whb,
    float* __restrict__ probe_out) {
  __shared__ __align__(1024) char lds[2 * LDSBUF];
  const int tid = threadIdx.x;
  const int wid = tid >> 6;
  const int lane = tid & 63;
  const int m0 = blockIdx.x * 128;
  const int n0 = blockIdx.y * 32;

  float4v acc[6][2][2];
#pragma unroll
  for (int g = 0; g < 6; ++g)
#pragma unroll
    for (int mf = 0; mf < 2; ++mf)
#pragma unroll
      for (int nf = 0; nf < 2; ++nf)
        acc[g][mf][nf] = (float4v)(0.0f);

  GRU_DESCRIPTORS

  if (MODE == 1) {  // stage once; then pure compute+barrier loop
    STAGE(0);
    asm volatile("s_waitcnt vmcnt(0)" ::: "memory");
    bar_sync();
#pragma unroll 1
    for (int it = 0; it < 100; ++it) {
      bar_sync();
      COMPUTE(0);
      bar_sync();
    }
  } else {
#pragma unroll 1
    for (int rep = 0; rep < 4; ++rep) {
#pragma unroll
      for (int s = 0; s < 7; ++s) gp[s] = gp0[s];   // rewind pointers each rep
      STAGE(0);
#pragma unroll 1
      for (int k = 0; k < 24; k += 2) {
        STAGE(1);
        asm volatile("s_waitcnt vmcnt(7)" ::: "memory");
        if (MODE != 3) bar_sync();
        if (MODE != 2) COMPUTE(0);
        if (MODE != 3) bar_sync();
        STAGE(0);
        asm volatile("s_waitcnt vmcnt(7)" ::: "memory");
        if (MODE != 3) bar_sync();
        if (MODE != 2) COMPUTE(1);
        if (MODE != 3) bar_sync();
      }
      asm volatile("s_waitcnt vmcnt(0)" ::: "memory");
      if (MODE != 3) bar_sync();
      if (MODE != 2) COMPUTE(0);
    }
  }

  // checksum keeps acc (and thus MFMA/ds_read chain) live; rule #17
  float cs = 0.0f;
#pragma unroll
  for (int g = 0; g < 6; ++g)
#pragma unroll
    for (int mf = 0; mf < 2; ++mf)
#pragma unroll
      for (int nf = 0; nf < 2; ++nf)
#pragma unroll
        for (int r = 0; r < 4; ++r) cs += acc[g][mf][nf][r];
  probe_out[(blockIdx.y * 16 + blockIdx.x) * 256 + tid] = cs + (float)ldso[0];
}

// ---------------- K_vec = h_new @ W_out^T + b_out, dropout m2, ens (2048 blocks) -------
__global__ void kvec_ens_kernel(const float* __restrict__ h_new,
                                const float* __restrict__ WoutT,
                                const float* __restrict__ b_out,
                                const float* __restrict__ x_pred,
                                const float* __restrict__ innov,
                                float* __restrict__ ens,
                                uint32_t k0, uint32_t k1) {
  const int jb = blockIdx.x;
  const int b = jb & (BATCH - 1);
  const int tid = threadIdx.x;
  const int o = tid & 31;
  const int kk = tid >> 5;

  const float* hrow = h_new + (size_t)jb * HID;
  float partial = 0.0f;
  for (int k = kk * 100; k < kk * 100 + 100; ++k)
    partial = fmaf(hrow[k], WoutT[k * 32 + o], partial);

  __shared__ float red[8][32];
  __shared__ float Kv[32];
  red[kk][o] = partial;
  __syncthreads();
  if (tid < 32) {
    float s = 0.0f;
#pragma unroll
    for (int q = 0; q < 8; ++q) s += red[q][tid];
    s += b_out[tid];
    float u = tf_uniform_part(k0, k1, (uint32_t)(jb * 32 + tid));
    Kv[tid] = (u < KEEPP) ? s * 1.25f : 0.0f;
  }
  __syncthreads();
  if (tid < SDIM) {
    float s = x_pred[b * SDIM + tid];
#pragma unroll
    for (int oo = 0; oo < ODIM; ++oo)
      s = fmaf(Kv[tid * ODIM + oo], innov[b * ODIM + oo], s);
    ens[jb * SDIM + tid] = s;
  }
}

// ---------------- ensemble stats + outputs + prep of next step (128 blocks) ------------
__global__ void reduce_prep_kernel(const float* __restrict__ ens,
                                   float* __restrict__ x_pred,
                                   float* __restrict__ innov,
                                   const float* __restrict__ y_seq,
                                   const float* __restrict__ W1,
                                   const float* __restrict__ b1,
                                   float* __restrict__ a,
                                   float* __restrict__ out_xs, float* __restrict__ out_Ps,
                                   int t) {
  const int b = blockIdx.x;
  const int tid = threadIdx.x;
  __shared__ float e[NSAMP][SDIM];
  __shared__ float xf[SDIM];
  __shared__ float dxs[SDIM];
  __shared__ float xpn[SDIM];
  __shared__ float inv[ODIM];
  __shared__ float nin[SDIM + ODIM];

  if (t >= 0) {
    if (tid < NSAMP * SDIM) {
      int j = tid >> 3, s = tid & 7;
      e[j][s] = ens[(j * BATCH + b) * SDIM + s];
    }
    __syncthreads();
    if (tid < SDIM) {
      float s = 0.0f;
#pragma unroll
      for (int j = 0; j < NSAMP; ++j) s += e[j][tid];
      s *= (1.0f / NSAMP);
      xf[tid] = s;
      out_xs[(b * SEQLEN + t) * SDIM + tid] = s;
      dxs[tid] = s - x_pred[b * SDIM + tid];
    }
    __syncthreads();
    if (tid < SDIM * SDIM) {
      int s = tid >> 3, u = tid & 7;
      float accv = 0.0f;
#pragma unroll
      for (int j = 0; j < NSAMP; ++j)
        accv += (e[j][s] - xf[s]) * (e[j][u] - xf[u]);
      out_Ps[((b * SEQLEN + t) * SDIM + s) * SDIM + u] = accv * (1.0f / NSAMP);
    }
  } else {
    if (tid < SDIM) { xf[tid] = 0.0f; dxs[tid] = 0.0f; }
  }
  if (t == SEQLEN - 1) return;
  __syncthreads();
  if (tid < SDIM) {
    float x = xf[tid];
    float xp = 0.9f * x + 0.1f * sinf(x);
    xpn[tid] = xp;
    x_pred[b * SDIM + tid] = xp;
  }
  __syncthreads();
  if (tid < ODIM) {
    float yh = tanhf(xpn[tid]);
    float iv = y_seq[(b * SEQLEN + (t + 1)) * ODIM + tid] - yh;
    inv[tid] = iv;
    innov[b * ODIM + tid] = iv;
  }
  __syncthreads();
  if (tid == 0) {
    float nd = 0.0f;
    for (int s = 0; s < SDIM; ++s) nd += dxs[s] * dxs[s];
    nd = fmaxf(sqrtf(nd), 1e-12f);
    for (int s = 0; s < SDIM; ++s) nin[s] = dxs[s] / nd;
    float ni = 0.0f;
    for (int o2 = 0; o2 < ODIM; ++o2) ni += inv[o2] * inv[o2];
    ni = fmaxf(sqrtf(ni), 1e-12f);
    for (int o2 = 0; o2 < ODIM; ++o2) nin[SDIM + o2] = inv[o2] / ni;
  }
  __syncthreads();
  for (int i = tid; i < HID; i += blockDim.x) {
    float s = b1[i];
#pragma unroll
    for (int c = 0; c < 12; ++c) s = fmaf(nin[c], W1[i * 12 + c], s);
    a[b * HID + i] = fmaxf(s, 0.0f);
  }
}

extern "C" void kernel_launch(void* const* d_in, const int* in_sizes, int n_in,
                              void* d_out, int out_size, void* d_ws, size_t ws_size,
                              hipStream_t stream) {
  (void)in_sizes; (void)n_in; (void)out_size; (void)ws_size;
  const float* y_seq = (const float*)d_in[0];
  const float* W1 = (const float*)d_in[1];
  const float* b1 = (const float*)d_in[2];
  const float* W_ih = (const float*)d_in[3];
  const float* W_hh = (const float*)d_in[4];
  const float* b_ih = (const float*)d_in[5];
  const float* b_hh = (const float*)d_in[6];
  const float* W_out = (const float*)d_in[7];
  const float* b_out = (const float*)d_in[8];

  char* ws = (char*)d_ws;
  size_t off = 0;
  float* h_a = (float*)(ws + off);    off += (size_t)MROWS * HID * 4;
  float* h_b = (float*)(ws + off);    off += (size_t)MROWS * HID * 4;
  ushort* hb_a = (ushort*)(ws + off); off += (size_t)MROWS * HID * 2;
  ushort* hb_b = (ushort*)(ws + off); off += (size_t)MROWS * HID * 2;
  ushort* aeb = (ushort*)(ws + off);  off += (size_t)MROWS * HID * 2;
  ushort* Wib = (ushort*)(ws + off);  off += (size_t)2400 * HID * 2;
  ushort* Whb = (ushort*)(ws + off);  off += (size_t)2400 * HID * 2;
  float* a_buf = (float*)(ws + off);  off += (size_t)BATCH * HID * 4;
  float* WoutT = (float*)(ws + off);  off += (size_t)HID * 32 * 4;
  float* x_pred = (float*)(ws + off); off += (size_t)BATCH * SDIM * 4;
  float* innov = (float*)(ws + off);  off += (size_t)BATCH * ODIM * 4;
  float* ens = (float*)(ws + off);    off += (size_t)NSAMP * BATCH * SDIM * 4;
  float* probe_out = (float*)(ws + off); off += (size_t)400 * 256 * 4;

  float* out_xs = (float*)d_out;
  float* out_Ps = out_xs + (size_t)BATCH * SEQLEN * SDIM;

  hipMemsetAsync(h_a, 0, (size_t)MROWS * HID * 4, stream);
  hipMemsetAsync(hb_a, 0, (size_t)MROWS * HID * 2, stream);
  convert_w_kernel<<<1875, 256, 0, stream>>>(W_ih, W_hh, Wib, Whb);
  transpose_wout_kernel<<<100, 256, 0, stream>>>(W_out, WoutT);
  reduce_prep_kernel<<<BATCH, 256, 0, stream>>>(ens, x_pred, innov, y_seq, W1, b1,
                                                a_buf, out_xs, out_Ps, -1);

  float* hc = h_a;  float* hn = h_b;
  ushort* hcb = hb_a; ushort* hnb = hb_b;
  dim3 gg(MROWS / 128, HID / 32);
  for (int t = 0; t < SEQLEN; ++t) {
    uint32_t kt0, kt1, k1a, k1b, k2a, k2b;
    tf2x32(0u, 42u, 0u, (uint32_t)t, kt0, kt1);   // fold_in(key(42), t)
    tf2x32(kt0, kt1, 0u, 0u, k1a, k1b);           // dropout1 key
    tf2x32(kt0, kt1, 0u, 1u, k2a, k2b);           // dropout2 key

    a_ens_kernel<<<1600, 256, 0, stream>>>(a_buf, aeb, k1a, k1b);
    gru_mfma_kernel<<<gg, 256, 0, stream>>>(aeb, hcb, Wib, Whb, hc, b_ih, b_hh, hn, hnb);
    kvec_ens_kernel<<<MROWS, 256, 0, stream>>>(hn, WoutT, b_out, x_pred, innov, ens, k2a, k2b);
    reduce_prep_kernel<<<BATCH, 256, 0, stream>>>(ens, x_pred, innov, y_seq, W1, b1,
                                                  a_buf, out_xs, out_Ps, t);
    float* tmp = hc; hc = hn; hn = tmp;
    ushort* tmpb = hcb; hcb = hnb; hnb = tmpb;
  }

  // ---- ablation probes (outputs unaffected; read final aeb/h state deterministically)
  gru_probe_kernel<0><<<gg, 256, 0, stream>>>(aeb, hcb, Wib, Whb, probe_out);
  gru_probe_kernel<1><<<gg, 256, 0, stream>>>(aeb, hcb, Wib, Whb, probe_out);
  gru_probe_kernel<2><<<gg, 256, 0, stream>>>(aeb, hcb, Wib, Whb, probe_out);
  gru_probe_kernel<3><<<gg, 256, 0, stream>>>(aeb, hcb, Wib, Whb, probe_out);
}

// Round 11
// 1703.004 us; speedup vs baseline: 1.4103x; 1.3070x over previous
//
#include <hip/hip_runtime.h>
#include <stdint.h>

#define NSAMP 16
#define BATCH 128
#define SEQLEN 32
#define SDIM 8
#define ODIM 4
#define HID 800
#define MROWS (NSAMP * BATCH) /* 2048 */
#define KEEPP 0.8f

typedef __attribute__((ext_vector_type(8))) short short8v;
typedef __attribute__((ext_vector_type(4))) float float4v;

// ---------------- threefry2x32 (JAX partitionable mode, verified R1) ----------------
__host__ __device__ __forceinline__ void tf2x32(uint32_t k0, uint32_t k1,
                                                uint32_t x0, uint32_t x1,
                                                uint32_t& o0, uint32_t& o1) {
  uint32_t ks2 = k0 ^ k1 ^ 0x1BD11BDAu;
  x0 += k0; x1 += k1;
#define TFR(r) { x0 += x1; x1 = (x1 << (r)) | (x1 >> (32 - (r))); x1 ^= x0; }
  TFR(13) TFR(15) TFR(26) TFR(6)
  x0 += k1; x1 += ks2 + 1u;
  TFR(17) TFR(29) TFR(16) TFR(24)
  x0 += ks2; x1 += k0 + 2u;
  TFR(13) TFR(15) TFR(26) TFR(6)
  x0 += k0; x1 += k1 + 3u;
  TFR(17) TFR(29) TFR(16) TFR(24)
  x0 += k1; x1 += ks2 + 4u;
  TFR(13) TFR(15) TFR(26) TFR(6)
  x0 += ks2; x1 += k0 + 5u;
#undef TFR
  o0 = x0; o1 = x1;
}

__device__ __forceinline__ float bits_to_unit(uint32_t bits) {
  return __uint_as_float((bits >> 9) | 0x3F800000u) - 1.0f;
}

__device__ __forceinline__ float tf_uniform_part(uint32_t k0, uint32_t k1, uint32_t idx) {
  uint32_t b1, b2;
  tf2x32(k0, k1, 0u, idx, b1, b2);
  return bits_to_unit(b1 ^ b2);
}

__device__ __forceinline__ ushort f2bf(float f) {
  uint32_t u = __float_as_uint(f);
  uint32_t r = (u + 0x7FFFu + ((u >> 16) & 1u)) >> 16;
  return (ushort)r;
}

__device__ __forceinline__ float bf2f(ushort u) {
  return __uint_as_float((uint32_t)u << 16);
}

__device__ __forceinline__ void bar_sync() {
  __builtin_amdgcn_sched_barrier(0);
  __builtin_amdgcn_s_barrier();
  __builtin_amdgcn_sched_barrier(0);
}

// ---------------- weight conversion fp32 -> bf16 (once) ----------------
__global__ void convert_w_kernel(const float* __restrict__ W_ih, const float* __restrict__ W_hh,
                                 ushort* __restrict__ Wib, ushort* __restrict__ Whb) {
  int i = (blockIdx.x * 256 + threadIdx.x) * 4;
  if (i >= 2400 * HID) return;
  float4 v1 = *reinterpret_cast<const float4*>(W_ih + i);
  float4 v2 = *reinterpret_cast<const float4*>(W_hh + i);
  ushort4 o1, o2;
  o1.x = f2bf(v1.x); o1.y = f2bf(v1.y); o1.z = f2bf(v1.z); o1.w = f2bf(v1.w);
  o2.x = f2bf(v2.x); o2.y = f2bf(v2.y); o2.z = f2bf(v2.z); o2.w = f2bf(v2.w);
  *reinterpret_cast<ushort4*>(Wib + i) = o1;
  *reinterpret_cast<ushort4*>(Whb + i) = o2;
}

__global__ void transpose_wout_kernel(const float* __restrict__ W_out, float* __restrict__ WoutT) {
  int i = blockIdx.x * 256 + threadIdx.x;
  if (i < 32 * HID) {
    int o = i / HID, k = i - o * HID;
    WoutT[k * 32 + o] = W_out[i];
  }
}

// ---------------- a_ens = bf16( a * m1 / keep ) ----------------
__global__ void a_ens_kernel(const float* __restrict__ a, ushort* __restrict__ aeb,
                             uint32_t k0, uint32_t k1) {
  int base = (blockIdx.x * blockDim.x + threadIdx.x) * 4;
  if (base >= MROWS * HID) return;
  int row = base / HID;
  int b = row % BATCH;
  int col = base - row * HID;
  float4 av = *reinterpret_cast<const float4*>(a + b * HID + col);
  ushort4 ov;
#pragma unroll
  for (int q = 0; q < 4; ++q) {
    float u = tf_uniform_part(k0, k1, (uint32_t)(base + q));
    float f = (&av.x)[q] * ((u < KEEPP) ? 1.25f : 0.0f);
    (&ov.x)[q] = f2bf(f);
  }
  *reinterpret_cast<ushort4*>(aeb + base) = ov;
}

// ====================== MFMA GRU (R4 K-loop, 45.6us-verified) + lean epilogue ==========
// h state is bf16-only. Epilogue: z*h_old term snapshotted from LDS (the h tile for
// k-range [n0,n0+32) passes through LDS at K-tile index blockIdx.y); only h_new_b (bf16,
// 3.3MB) is written. Removes 13.1MB/dispatch of fp32 h traffic (~17us -> ~3us measured
// epilogue cost per R10 ablation: K-loop=28.5us of the 45.6us dispatch).
#define LDSBUF 28672

__global__ __launch_bounds__(256, 2) void gru_mfma_kernel(
    const ushort* __restrict__ aeb, const ushort* __restrict__ hb,
    const ushort* __restrict__ Wib, const ushort* __restrict__ Whb,
    const float* __restrict__ b_ih, const float* __restrict__ b_hh,
    ushort* __restrict__ h_new_b) {
  __shared__ __align__(1024) char lds[2 * LDSBUF];
  const int tid = threadIdx.x;
  const int wid = tid >> 6;
  const int lane = tid & 63;
  const int m0 = blockIdx.x * 128;
  const int by = blockIdx.y;           // 0..24 == K-tile index owning cols [n0,n0+32)
  const int n0 = by * 32;

  float4v acc[6][2][2];
#pragma unroll
  for (int g = 0; g < 6; ++g)
#pragma unroll
    for (int mf = 0; mf < 2; ++mf)
#pragma unroll
      for (int nf = 0; nf < 2; ++nf)
        acc[g][mf][nf] = (float4v)(0.0f);

  const int rlo = lane >> 2;
  const int sslot = (lane & 3) ^ ((lane >> 3) & 3);
  const int kg = lane >> 4;
  const int l15 = lane & 15;
  const int rowq = (lane >> 4) * 4;

  const ushort* gp[7];
  int ldso[7];
#pragma unroll
  for (int s = 0; s < 7; ++s) {
    int i = s * 4 + wid;
    if (i < 16) {
      int src = i >> 3, i8 = i & 7;
      ldso[s] = src * 8192 + i8 * 1024;
      const ushort* base = src ? hb : aeb;
      gp[s] = base + (size_t)(m0 + i8 * 16 + rlo) * HID + sslot * 8;
    } else {
      int j = i - 16, g = j >> 1, half = j & 1;
      ldso[s] = 16384 + g * 2048 + half * 1024;
      const ushort* base = (g < 3) ? Wib : Whb;
      int wrow = n0 + (g % 3) * HID + half * 16 + rlo;
      gp[s] = base + (size_t)wrow * HID + sslot * 8;
    }
  }

  ushort hsnap[2][2][4];   // h_old[m][n0+...] snapshot, filled at K-tile == by

#define STAGE(BUF) do {                                                          \
    _Pragma("unroll")                                                            \
    for (int s = 0; s < 7; ++s) {                                                \
      __builtin_amdgcn_global_load_lds(                                          \
          (const __attribute__((address_space(1))) void*)gp[s],                  \
          (__attribute__((address_space(3))) void*)(lds + (BUF)*LDSBUF + ldso[s]),\
          16, 0, 0);                                                             \
      gp[s] += 32;                                                               \
    }                                                                            \
  } while (0)

// read h_old fragment for cols [n0,n0+32) out of the staged h A-tile (src=1 region):
// h[local row rr][kk] lives at byte 8192 + rr*64 + (((kk>>3) ^ ((rr>>1)&3))<<4) + (kk&7)*2
#define SNAP(BUF) do {                                                           \
    _Pragma("unroll")                                                            \
    for (int mf = 0; mf < 2; ++mf)                                               \
      _Pragma("unroll")                                                          \
      for (int nf = 0; nf < 2; ++nf)                                             \
        _Pragma("unroll")                                                        \
        for (int reg = 0; reg < 4; ++reg) {                                      \
          int rr = wid * 32 + mf * 16 + rowq + reg;                              \
          int kk = nf * 16 + l15;                                                \
          int off = (BUF) * LDSBUF + 8192 + rr * 64 +                            \
                    ((((kk >> 3) ^ ((rr >> 1) & 3))) << 4) + (kk & 7) * 2;       \
          hsnap[mf][nf][reg] = *reinterpret_cast<const ushort*>(lds + off);      \
        }                                                                        \
  } while (0)

#define COMPUTE(BUF) do {                                                        \
    const char* lb = lds + (BUF)*LDSBUF;                                         \
    short8v bfr[6][2];                                                           \
    _Pragma("unroll")                                                            \
    for (int g = 0; g < 6; ++g)                                                  \
      _Pragma("unroll")                                                          \
      for (int nf = 0; nf < 2; ++nf) {                                           \
        int row = nf * 16 + l15;                                                 \
        int off = 16384 + g * 2048 + row * 64 + ((kg ^ ((row >> 1) & 3)) << 4);  \
        bfr[g][nf] = *reinterpret_cast<const short8v*>(lb + off);                \
      }                                                                          \
    short8v afr[2][2];                                                           \
    _Pragma("unroll")                                                            \
    for (int src = 0; src < 2; ++src)                                            \
      _Pragma("unroll")                                                          \
      for (int mf = 0; mf < 2; ++mf) {                                           \
        int row = wid * 32 + mf * 16 + l15;                                      \
        int off = src * 8192 + row * 64 + ((kg ^ ((row >> 1) & 3)) << 4);        \
        afr[src][mf] = *reinterpret_cast<const short8v*>(lb + off);              \
      }                                                                          \
    _Pragma("unroll")                                                            \
    for (int g = 0; g < 6; ++g) {                                                \
      const int src = (g < 3) ? 0 : 1;                                           \
      _Pragma("unroll")                                                          \
      for (int mf = 0; mf < 2; ++mf)                                             \
        _Pragma("unroll")                                                        \
        for (int nf = 0; nf < 2; ++nf)                                           \
          acc[g][mf][nf] = __builtin_amdgcn_mfma_f32_16x16x32_bf16(              \
              afr[src][mf], bfr[g][nf], acc[g][mf][nf], 0, 0, 0);                \
    }                                                                            \
  } while (0)

  STAGE(0);
#pragma unroll 1
  for (int k = 0; k < 24; k += 2) {
    STAGE(1);
    asm volatile("s_waitcnt vmcnt(7)" ::: "memory");
    bar_sync();
    if (k == by) SNAP(0);          // by even, tile k in buffer 0
    COMPUTE(0);
    bar_sync();
    STAGE(0);
    asm volatile("s_waitcnt vmcnt(7)" ::: "memory");
    bar_sync();
    if (k + 1 == by) SNAP(1);      // by odd, tile k+1 in buffer 1
    COMPUTE(1);
    bar_sync();
  }
  asm volatile("s_waitcnt vmcnt(0)" ::: "memory");
  bar_sync();
  if (by == 24) SNAP(0);           // final tile 24 in buffer 0
  COMPUTE(0);

  // ---- epilogue: gates + state; C/D: col=lane&15, row=(lane>>4)*4+reg
#pragma unroll
  for (int nf = 0; nf < 2; ++nf) {
    const int col = n0 + nf * 16 + l15;
    const float bir = b_ih[col], biz = b_ih[col + HID], bin = b_ih[col + 2 * HID];
    const float bhr = b_hh[col], bhz = b_hh[col + HID], bhn = b_hh[col + 2 * HID];
#pragma unroll
    for (int mf = 0; mf < 2; ++mf) {
#pragma unroll
      for (int reg = 0; reg < 4; ++reg) {
        const int m = m0 + wid * 32 + mf * 16 + rowq + reg;
        float gir = acc[0][mf][nf][reg] + bir;
        float giz = acc[1][mf][nf][reg] + biz;
        float gin = acc[2][mf][nf][reg] + bin;
        float ghr = acc[3][mf][nf][reg] + bhr;
        float ghz = acc[4][mf][nf][reg] + bhz;
        float ghn = acc[5][mf][nf][reg] + bhn;
        float r = 1.0f / (1.0f + expf(-(gir + ghr)));
        float z = 1.0f / (1.0f + expf(-(giz + ghz)));
        float nval = tanhf(gin + r * ghn);
        float hv = bf2f(hsnap[mf][nf][reg]);
        float res = (1.0f - z) * nval + z * hv;
        h_new_b[(size_t)m * HID + col] = f2bf(res);
      }
    }
  }
#undef STAGE
#undef SNAP
#undef COMPUTE
}

// ---------------- K_vec = h_new(bf16) @ W_out^T + b_out, dropout m2, ens ----------------
__global__ void kvec_ens_kernel(const ushort* __restrict__ hnb,
                                const float* __restrict__ WoutT,  // [HID][32]
                                const float* __restrict__ b_out,
                                const float* __restrict__ x_pred, // [B][8]
                                const float* __restrict__ innov,  // [B][4]
                                float* __restrict__ ens,          // [NS][B][8]
                                uint32_t k0, uint32_t k1) {
  const int jb = blockIdx.x;
  const int b = jb & (BATCH - 1);
  const int tid = threadIdx.x;
  const int o = tid & 31;
  const int kk = tid >> 5;

  const ushort* hrow = hnb + (size_t)jb * HID + kk * 100;
  const float* wc = WoutT + kk * 100 * 32 + o;
  float partial = 0.0f;
  for (int k = 0; k < 100; ++k)
    partial = fmaf(bf2f(hrow[k]), wc[k * 32], partial);

  __shared__ float red[8][32];
  __shared__ float Kv[32];
  red[kk][o] = partial;
  __syncthreads();
  if (tid < 32) {
    float s = 0.0f;
#pragma unroll
    for (int q = 0; q < 8; ++q) s += red[q][tid];
    s += b_out[tid];
    float u = tf_uniform_part(k0, k1, (uint32_t)(jb * 32 + tid));
    Kv[tid] = (u < KEEPP) ? s * 1.25f : 0.0f;
  }
  __syncthreads();
  if (tid < SDIM) {
    float s = x_pred[b * SDIM + tid];
#pragma unroll
    for (int oo = 0; oo < ODIM; ++oo)
      s = fmaf(Kv[tid * ODIM + oo], innov[b * ODIM + oo], s);
    ens[jb * SDIM + tid] = s;
  }
}

// ---------------- ensemble stats + outputs + prep of next step (128 blocks) ------------
__global__ void reduce_prep_kernel(const float* __restrict__ ens,
                                   float* __restrict__ x_pred,
                                   float* __restrict__ innov,
                                   const float* __restrict__ y_seq,
                                   const float* __restrict__ W1,
                                   const float* __restrict__ b1,
                                   float* __restrict__ a,
                                   float* __restrict__ out_xs, float* __restrict__ out_Ps,
                                   int t) {
  const int b = blockIdx.x;
  const int tid = threadIdx.x;
  __shared__ float e[NSAMP][SDIM];
  __shared__ float xf[SDIM];
  __shared__ float dxs[SDIM];
  __shared__ float xpn[SDIM];
  __shared__ float inv[ODIM];
  __shared__ float nin[SDIM + ODIM];

  if (t >= 0) {
    if (tid < NSAMP * SDIM) {
      int j = tid >> 3, s = tid & 7;
      e[j][s] = ens[(j * BATCH + b) * SDIM + s];
    }
    __syncthreads();
    if (tid < SDIM) {
      float s = 0.0f;
#pragma unroll
      for (int j = 0; j < NSAMP; ++j) s += e[j][tid];
      s *= (1.0f / NSAMP);
      xf[tid] = s;
      out_xs[(b * SEQLEN + t) * SDIM + tid] = s;
      dxs[tid] = s - x_pred[b * SDIM + tid];
    }
    __syncthreads();
    if (tid < SDIM * SDIM) {
      int s = tid >> 3, u = tid & 7;
      float accv = 0.0f;
#pragma unroll
      for (int j = 0; j < NSAMP; ++j)
        accv += (e[j][s] - xf[s]) * (e[j][u] - xf[u]);
      out_Ps[((b * SEQLEN + t) * SDIM + s) * SDIM + u] = accv * (1.0f / NSAMP);
    }
  } else {
    if (tid < SDIM) { xf[tid] = 0.0f; dxs[tid] = 0.0f; }
  }
  if (t == SEQLEN - 1) return;
  __syncthreads();
  if (tid < SDIM) {
    float x = xf[tid];
    float xp = 0.9f * x + 0.1f * sinf(x);
    xpn[tid] = xp;
    x_pred[b * SDIM + tid] = xp;
  }
  __syncthreads();
  if (tid < ODIM) {
    float yh = tanhf(xpn[tid]);
    float iv = y_seq[(b * SEQLEN + (t + 1)) * ODIM + tid] - yh;
    inv[tid] = iv;
    innov[b * ODIM + tid] = iv;
  }
  __syncthreads();
  if (tid == 0) {
    float nd = 0.0f;
    for (int s = 0; s < SDIM; ++s) nd += dxs[s] * dxs[s];
    nd = fmaxf(sqrtf(nd), 1e-12f);
    for (int s = 0; s < SDIM; ++s) nin[s] = dxs[s] / nd;
    float ni = 0.0f;
    for (int o2 = 0; o2 < ODIM; ++o2) ni += inv[o2] * inv[o2];
    ni = fmaxf(sqrtf(ni), 1e-12f);
    for (int o2 = 0; o2 < ODIM; ++o2) nin[SDIM + o2] = inv[o2] / ni;
  }
  __syncthreads();
  for (int i = tid; i < HID; i += blockDim.x) {
    float s = b1[i];
#pragma unroll
    for (int c = 0; c < 12; ++c) s = fmaf(nin[c], W1[i * 12 + c], s);
    a[b * HID + i] = fmaxf(s, 0.0f);
  }
}

extern "C" void kernel_launch(void* const* d_in, const int* in_sizes, int n_in,
                              void* d_out, int out_size, void* d_ws, size_t ws_size,
                              hipStream_t stream) {
  (void)in_sizes; (void)n_in; (void)out_size; (void)ws_size;
  const float* y_seq = (const float*)d_in[0];
  const float* W1 = (const float*)d_in[1];
  const float* b1 = (const float*)d_in[2];
  const float* W_ih = (const float*)d_in[3];
  const float* W_hh = (const float*)d_in[4];
  const float* b_ih = (const float*)d_in[5];
  const float* b_hh = (const float*)d_in[6];
  const float* W_out = (const float*)d_in[7];
  const float* b_out = (const float*)d_in[8];

  char* ws = (char*)d_ws;
  size_t off = 0;
  ushort* hb_a = (ushort*)(ws + off); off += (size_t)MROWS * HID * 2;
  ushort* hb_b = (ushort*)(ws + off); off += (size_t)MROWS * HID * 2;
  ushort* aeb = (ushort*)(ws + off);  off += (size_t)MROWS * HID * 2;
  ushort* Wib = (ushort*)(ws + off);  off += (size_t)2400 * HID * 2;
  ushort* Whb = (ushort*)(ws + off);  off += (size_t)2400 * HID * 2;
  float* a_buf = (float*)(ws + off);  off += (size_t)BATCH * HID * 4;
  float* WoutT = (float*)(ws + off);  off += (size_t)HID * 32 * 4;
  float* x_pred = (float*)(ws + off); off += (size_t)BATCH * SDIM * 4;
  float* innov = (float*)(ws + off);  off += (size_t)BATCH * ODIM * 4;
  float* ens = (float*)(ws + off);    off += (size_t)NSAMP * BATCH * SDIM * 4;

  float* out_xs = (float*)d_out;
  float* out_Ps = out_xs + (size_t)BATCH * SEQLEN * SDIM;

  hipMemsetAsync(hb_a, 0, (size_t)MROWS * HID * 2, stream);
  convert_w_kernel<<<1875, 256, 0, stream>>>(W_ih, W_hh, Wib, Whb);
  transpose_wout_kernel<<<100, 256, 0, stream>>>(W_out, WoutT);
  reduce_prep_kernel<<<BATCH, 256, 0, stream>>>(ens, x_pred, innov, y_seq, W1, b1,
                                                a_buf, out_xs, out_Ps, -1);

  ushort* hcb = hb_a; ushort* hnb = hb_b;
  dim3 gg(MROWS / 128, HID / 32);
  for (int t = 0; t < SEQLEN; ++t) {
    uint32_t kt0, kt1, k1a, k1b, k2a, k2b;
    tf2x32(0u, 42u, 0u, (uint32_t)t, kt0, kt1);   // fold_in(key(42), t)
    tf2x32(kt0, kt1, 0u, 0u, k1a, k1b);           // dropout1 key
    tf2x32(kt0, kt1, 0u, 1u, k2a, k2b);           // dropout2 key

    a_ens_kernel<<<1600, 256, 0, stream>>>(a_buf, aeb, k1a, k1b);
    gru_mfma_kernel<<<gg, 256, 0, stream>>>(aeb, hcb, Wib, Whb, b_ih, b_hh, hnb);
    kvec_ens_kernel<<<MROWS, 256, 0, stream>>>(hnb, WoutT, b_out, x_pred, innov, ens, k2a, k2b);
    reduce_prep_kernel<<<BATCH, 256, 0, stream>>>(ens, x_pred, innov, y_seq, W1, b1,
                                                  a_buf, out_xs, out_Ps, t);
    ushort* tmpb = hcb; hcb = hnb; hnb = tmpb;
  }
}